// Round 3
// baseline (493.861 us; speedup 1.0000x reference)
//
#include <hip/hip_runtime.h>
#include <stdint.h>

typedef unsigned short u16;
typedef short bf16x8 __attribute__((ext_vector_type(8)));
typedef float f32x4 __attribute__((ext_vector_type(4)));
typedef u16 u16x8 __attribute__((ext_vector_type(8)));
typedef u16 u16x4 __attribute__((ext_vector_type(4)));

#define NB 8
#define NS 1024
#define NH 16
#define NDH 64
#define ND 1024

#define AS1 __attribute__((address_space(1)))
#define AS3 __attribute__((address_space(3)))

// swizzled byte offset for u2/w2: row stride 128B, XOR row&7 into byte bits 4..6
__device__ __forceinline__ int SWZ(int row, int colbyte){
  return (row << 7) + (colbyte ^ ((row & 7) << 4));
}

__device__ __forceinline__ u16 f2b(float x){
  unsigned u = __float_as_uint(x);
  u += 0x7FFFu + ((u >> 16) & 1u);          // RNE
  return (u16)(u >> 16);
}
__device__ __forceinline__ float b2f(u16 h){ return __uint_as_float(((unsigned)h) << 16); }

// ---------------- cast f32 -> bf16 (n multiple of 8) ----------------
__global__ void cast_f32_bf16(const float* __restrict__ in, u16* __restrict__ out, long n){
  long i = ((long)blockIdx.x * blockDim.x + threadIdx.x) * 8;
  if (i + 8 <= n){
    float4 a = *(const float4*)&in[i];
    float4 b = *(const float4*)&in[i + 4];
    u16x8 o;
    o[0]=f2b(a.x); o[1]=f2b(a.y); o[2]=f2b(a.z); o[3]=f2b(a.w);
    o[4]=f2b(b.x); o[5]=f2b(b.y); o[6]=f2b(b.z); o[7]=f2b(b.w);
    *(u16x8*)&out[i] = o;
  }
}

// ---------------- transpose W (fp32 [k][n]) -> wt bf16 [p*1024+n][k] ----------------
__global__ void transpose_w(const float* __restrict__ Wq, const float* __restrict__ Wk,
                            const float* __restrict__ Wv, u16* __restrict__ wt){
  __shared__ float tile[64][65];
  int p = blockIdx.z;
  const float* W = (p == 0) ? Wq : ((p == 1) ? Wk : Wv);
  int n0 = blockIdx.x * 64, k0 = blockIdx.y * 64;
  int t = threadIdx.x;
  int row = t >> 2, cb = (t & 3) * 16;
  #pragma unroll
  for (int cc = 0; cc < 4; ++cc){
    float4 v = *(const float4*)&W[(size_t)(k0 + row) * ND + n0 + cb + cc * 4];
    tile[row][cb + cc*4 + 0] = v.x; tile[row][cb + cc*4 + 1] = v.y;
    tile[row][cb + cc*4 + 2] = v.z; tile[row][cb + cc*4 + 3] = v.w;
  }
  __syncthreads();
  u16x8 o0, o1;
  #pragma unroll
  for (int kk = 0; kk < 8; ++kk) o0[kk] = f2b(tile[cb + kk][row]);
  #pragma unroll
  for (int kk = 0; kk < 8; ++kk) o1[kk] = f2b(tile[cb + 8 + kk][row]);
  size_t ob = ((size_t)(p * ND + n0 + row)) * ND + k0 + cb;
  *(u16x8*)&wt[ob]     = o0;
  *(u16x8*)&wt[ob + 8] = o1;
}

// ---------------- QKV GEMM (unchanged from R0) ----------------
__global__ __launch_bounds__(256) void qkv_gemm(
    const u16* __restrict__ hsb, const u16* __restrict__ wtb,
    const float* __restrict__ bq, const float* __restrict__ bk, const float* __restrict__ bv,
    u16* __restrict__ qb, u16* __restrict__ kb, u16* __restrict__ vt){
  __shared__ __attribute__((aligned(16))) u16 Al[128 * 32];
  __shared__ __attribute__((aligned(16))) u16 Bl[128 * 32];
  int t = threadIdx.x;
  int lane = t & 63, w = t >> 6;
  int li = lane & 15, g = lane >> 4;
  int m0 = blockIdx.y * 128, n0 = blockIdx.x * 128;
  int wm = (w >> 1) * 64, wn = (w & 1) * 64;
  f32x4 acc[4][4];
  #pragma unroll
  for (int a = 0; a < 4; ++a)
    #pragma unroll
    for (int b = 0; b < 4; ++b){ f32x4 z = {0.f,0.f,0.f,0.f}; acc[a][b] = z; }

  for (int kt = 0; kt < 32; ++kt){
    __syncthreads();
    #pragma unroll
    for (int ph = 0; ph < 2; ++ph){
      int c = ph * 256 + t;            // chunk 0..511 (16B each)
      int row = c >> 2, ch = c & 3;
      const u16* ga = &hsb[(size_t)(m0 + row) * ND + kt * 32 + ch * 8];
      __builtin_amdgcn_global_load_lds((const AS1 void*)ga,
          (AS3 void*)&Al[(ph * 256 + w * 64) * 8], 16, 0, 0);
      const u16* gb = &wtb[(size_t)(n0 + row) * ND + kt * 32 + ch * 8];
      __builtin_amdgcn_global_load_lds((const AS1 void*)gb,
          (AS3 void*)&Bl[(ph * 256 + w * 64) * 8], 16, 0, 0);
    }
    asm volatile("s_waitcnt vmcnt(0)" ::: "memory");
    __syncthreads();
    bf16x8 af[4], bfr[4];
    #pragma unroll
    for (int mt = 0; mt < 4; ++mt)
      af[mt] = *(const bf16x8*)&Al[(wm + mt * 16 + li) * 32 + g * 8];
    #pragma unroll
    for (int nt = 0; nt < 4; ++nt)
      bfr[nt] = *(const bf16x8*)&Bl[(wn + nt * 16 + li) * 32 + g * 8];
    #pragma unroll
    for (int mt = 0; mt < 4; ++mt)
      #pragma unroll
      for (int nt = 0; nt < 4; ++nt)
        acc[mt][nt] = __builtin_amdgcn_mfma_f32_16x16x32_bf16(af[mt], bfr[nt], acc[mt][nt], 0, 0, 0);
  }

  int proj = n0 >> 10;
  const float* bias = (proj == 0) ? bq : ((proj == 1) ? bk : bv);
  #pragma unroll
  for (int nt = 0; nt < 4; ++nt){
    int n = n0 + wn + nt * 16 + li;
    int nc = n & 1023;
    float bv_ = bias[nc];
    #pragma unroll
    for (int mt = 0; mt < 4; ++mt){
      #pragma unroll
      for (int r = 0; r < 4; ++r){
        int m = m0 + wm + mt * 16 + g * 4 + r;
        u16 hv = f2b(acc[mt][nt][r] + bv_);
        if (proj == 0)      qb[(size_t)m * ND + nc] = hv;
        else if (proj == 1) kb[(size_t)m * ND + nc] = hv;
        else {
          int bb = m >> 10, s = m & 1023;
          int hh = nc >> 6, dh = nc & 63;
          vt[((size_t)(bb * NH + hh) * NDH + dh) * NS + s] = hv;
        }
      }
    }
  }
}

// ---------------- fused flash attention with relative_key_query bias ----------------
// R0 structure + three changes: (1) E frags read direct from global (no e_lds),
// (2) u2/w2 XOR-swizzled stride-64, (3) LDS 50KB -> 3 blocks/CU.
// K/V staging + QK^T/PV layout identical to R0 (stride-72, reg-staged).
__global__ __launch_bounds__(256, 3) void attn(
    const u16* __restrict__ qb, const u16* __restrict__ kb,
    const u16* __restrict__ vt, const u16* __restrict__ eb,
    const float* __restrict__ mask, float* __restrict__ out){
  __shared__ __attribute__((aligned(16))) u16 k_lds[64 * 72];
  __shared__ __attribute__((aligned(16))) u16 v_lds[64 * 72];
  __shared__ __attribute__((aligned(16))) u16 u2[128 * 64];   // U2[tt][i], swizzled; rows 0..63 reused as P
  __shared__ __attribute__((aligned(16))) u16 w2[128 * 64];   // W2[tt][j], swizzled

  int t = threadIdx.x, lane = t & 63, w = t >> 6;
  int li = lane & 15, g = lane >> 4;
  int lt = blockIdx.x, bh = blockIdx.y;
  int b = bh >> 4, h = bh & 15;
  int l0 = lt * 64;
  int iA  = w * 16 + g * 4;          // i base for this lane's score rows
  int iA2 = iA * 2;
  int li2 = li * 2;
  int ttc = iA + 63 - li;            // tt = ttc + r - 16*jt
  int colw = iA2;                    // u2/w2 write column byte base

  // Q A-frags (16 rows per wave), resident for all 16 K-tiles
  bf16x8 qf[2];
  {
    size_t qoff = ((size_t)(b * NS + l0 + w * 16 + li)) * ND + h * NDH;
    qf[0] = *(const bf16x8*)&qb[qoff + 0 + g * 8];
    qf[1] = *(const bf16x8*)&qb[qoff + 32 + g * 8];
  }
  f32x4 oacc[4];
  #pragma unroll
  for (int i = 0; i < 4; ++i){ f32x4 z = {0.f,0.f,0.f,0.f}; oacc[i] = z; }
  float mold[4] = {-1e30f, -1e30f, -1e30f, -1e30f};
  float lsum[4] = {0.f, 0.f, 0.f, 0.f};

  for (int kt2 = 0; kt2 < 16; ++kt2){
    int r0 = kt2 * 64;
    int ebase = l0 - r0 + 960;       // window t_glob in [ebase, ebase+127]

    __syncthreads();                 // b0: prev iter PV reads done before restage
    {
      u16x8 rk[2], rv[2];
      #pragma unroll
      for (int ph = 0; ph < 2; ++ph){
        int c = ph * 256 + t, row = c >> 3, ch = c & 7;
        rk[ph] = *(const u16x8*)&kb[((size_t)(b * NS + r0 + row)) * ND + h * NDH + ch * 8];
        rv[ph] = *(const u16x8*)&vt[((size_t)(bh * NDH + row)) * NS + r0 + ch * 8];
      }
      #pragma unroll
      for (int ph = 0; ph < 2; ++ph){
        int c = ph * 256 + t, row = c >> 3, ch = c & 7;
        *(u16x8*)&k_lds[row * 72 + ch * 8] = rk[ph];
        *(u16x8*)&v_lds[row * 72 + ch * 8] = rv[ph];
      }
    }
    __syncthreads();                 // b1: k/v staged

    // k A-frags (this wave's 16 j rows) for W2
    bf16x8 kf[2];
    kf[0] = *(const bf16x8*)&k_lds[(w * 16 + li) * 72 + 0 + g * 8];
    kf[1] = *(const bf16x8*)&k_lds[(w * 16 + li) * 72 + 32 + g * 8];

    // U2[t][i] = q_i . e[t] ; W2[t][j] = k_j . e[t]  — E frags direct from global
    #pragma unroll
    for (int nt = 0; nt < 8; ++nt){
      int trow = nt * 16 + li;
      int er = ebase + trow; if (er > 2046) er = 2046;   // row 127 never gathered
      f32x4 ua = {0.f,0.f,0.f,0.f}, wa = {0.f,0.f,0.f,0.f};
      #pragma unroll
      for (int k2 = 0; k2 < 2; ++k2){
        bf16x8 ef = *(const bf16x8*)&eb[(size_t)er * NDH + k2 * 32 + g * 8];
        ua = __builtin_amdgcn_mfma_f32_16x16x32_bf16(qf[k2], ef, ua, 0, 0, 0);
        wa = __builtin_amdgcn_mfma_f32_16x16x32_bf16(kf[k2], ef, wa, 0, 0, 0);
      }
      u16x4 up, wp;
      #pragma unroll
      for (int r = 0; r < 4; ++r){ up[r] = f2b(ua[r]); wp[r] = f2b(wa[r]); }
      *(u16x4*)((char*)u2 + SWZ(trow, colw)) = up;
      *(u16x4*)((char*)w2 + SWZ(trow, colw)) = wp;
    }

    // QK^T: this wave's 16 q-rows x 64 cols
    f32x4 sacc[4];
    #pragma unroll
    for (int jt = 0; jt < 4; ++jt){
      f32x4 z = {0.f,0.f,0.f,0.f}; sacc[jt] = z;
      #pragma unroll
      for (int k2 = 0; k2 < 2; ++k2){
        bf16x8 kbf = *(const bf16x8*)&k_lds[(jt * 16 + li) * 72 + k2 * 32 + g * 8];
        sacc[jt] = __builtin_amdgcn_mfma_f32_16x16x32_bf16(qf[k2], kbf, sacc[jt], 0, 0, 0);
      }
    }
    __syncthreads();                 // b2: U2/W2 visible

    // gather diagonal bias + assemble scores
    float sv[4][4];
    #pragma unroll
    for (int jt = 0; jt < 4; ++jt){
      float mk = mask[b * NS + r0 + jt * 16 + li];
      int j2 = jt * 32 + li2;
      #pragma unroll
      for (int r = 0; r < 4; ++r){
        int tt = ttc + r - jt * 16;
        int byU = (tt << 7) + ((iA2 + 2 * r) ^ ((tt & 7) << 4));
        int byW = (tt << 7) + (j2 ^ ((tt & 7) << 4));
        float u  = b2f(*(const u16*)((const char*)u2 + byU));
        float ww = b2f(*(const u16*)((const char*)w2 + byW));
        sv[jt][r] = sacc[jt][r] * 0.125f + u + ww + mk;
      }
    }

    // online softmax (rows live in 16-lane groups)
    float rmax[4], rsum[4];
    #pragma unroll
    for (int r = 0; r < 4; ++r)
      rmax[r] = fmaxf(fmaxf(sv[0][r], sv[1][r]), fmaxf(sv[2][r], sv[3][r]));
    #pragma unroll
    for (int xm = 1; xm <= 8; xm <<= 1)
      #pragma unroll
      for (int r = 0; r < 4; ++r)
        rmax[r] = fmaxf(rmax[r], __shfl_xor(rmax[r], xm));
    float mnew[4], fac[4];
    #pragma unroll
    for (int r = 0; r < 4; ++r){
      mnew[r] = fmaxf(mold[r], rmax[r]);
      fac[r]  = __expf(mold[r] - mnew[r]);
    }
    float pr[4][4];
    #pragma unroll
    for (int r = 0; r < 4; ++r) rsum[r] = 0.f;
    #pragma unroll
    for (int jt = 0; jt < 4; ++jt)
      #pragma unroll
      for (int r = 0; r < 4; ++r){
        pr[jt][r] = __expf(sv[jt][r] - mnew[r]);
        rsum[r] += pr[jt][r];
      }
    #pragma unroll
    for (int xm = 1; xm <= 8; xm <<= 1)
      #pragma unroll
      for (int r = 0; r < 4; ++r)
        rsum[r] += __shfl_xor(rsum[r], xm);
    #pragma unroll
    for (int r = 0; r < 4; ++r){
      lsum[r] = lsum[r] * fac[r] + rsum[r];
      mold[r] = mnew[r];
    }
    #pragma unroll
    for (int nt2 = 0; nt2 < 4; ++nt2)
      #pragma unroll
      for (int r = 0; r < 4; ++r)
        oacc[nt2][r] *= fac[r];

    __syncthreads();                 // b3: gathers done; u2 rows 0..63 reusable as P
    #pragma unroll
    for (int jt = 0; jt < 4; ++jt)
      #pragma unroll
      for (int r = 0; r < 4; ++r){
        int prow = w * 16 + g * 4 + r;
        *(u16*)((char*)u2 + SWZ(prow, jt * 32 + li2)) = f2b(pr[jt][r]);
      }

    // PV: O += P @ V   (A=P rows i from u2 strip, B=V^T rows dh from v_lds)
    #pragma unroll
    for (int k2 = 0; k2 < 2; ++k2){
      bf16x8 pf = *(const bf16x8*)((const char*)u2 + SWZ(w * 16 + li, k2 * 64 + g * 16));
      #pragma unroll
      for (int nt2 = 0; nt2 < 4; ++nt2){
        bf16x8 vf = *(const bf16x8*)&v_lds[(nt2 * 16 + li) * 72 + k2 * 32 + g * 8];
        oacc[nt2] = __builtin_amdgcn_mfma_f32_16x16x32_bf16(pf, vf, oacc[nt2], 0, 0, 0);
      }
    }
  }

  // epilogue: O / lsum -> out fp32 [B,S,D]
  #pragma unroll
  for (int nt2 = 0; nt2 < 4; ++nt2)
    #pragma unroll
    for (int r = 0; r < 4; ++r){
      int row = l0 + w * 16 + g * 4 + r;
      out[((size_t)(b * NS + row)) * ND + h * NDH + nt2 * 16 + li] = oacc[nt2][r] / lsum[r];
    }
}

extern "C" void kernel_launch(void* const* d_in, const int* in_sizes, int n_in,
                              void* d_out, int out_size, void* d_ws, size_t ws_size,
                              hipStream_t stream){
  (void)in_sizes; (void)n_in; (void)out_size; (void)ws_size;
  const float* hs   = (const float*)d_in[0];
  const float* mask = (const float*)d_in[1];
  const float* Wq   = (const float*)d_in[2];
  const float* bq   = (const float*)d_in[3];
  const float* Wk   = (const float*)d_in[4];
  const float* bk   = (const float*)d_in[5];
  const float* Wv   = (const float*)d_in[6];
  const float* bv   = (const float*)d_in[7];
  const float* de   = (const float*)d_in[8];
  float* out = (float*)d_out;
  char* ws = (char*)d_ws;

  u16* hsb = (u16*)(ws);                    // 16,777,216 B
  u16* wtb = (u16*)(ws + 16777216);         //  6,291,456 B
  u16* eb  = (u16*)(ws + 23068672);         //    262,016 B (+pad)
  u16* qb  = (u16*)(ws + 23330816);         // 16,777,216 B
  u16* kb  = (u16*)(ws + 40108032);         // 16,777,216 B
  u16* vt  = (u16*)(ws + 56885248);         // 16,777,216 B  -> total ~70.2 MB

  cast_f32_bf16<<<4096, 256, 0, stream>>>(hs, hsb, 8388608L);
  cast_f32_bf16<<<64, 256, 0, stream>>>(de, eb, 131008L);
  transpose_w<<<dim3(16, 16, 3), 256, 0, stream>>>(Wq, Wk, Wv, wtb);
  qkv_gemm<<<dim3(24, 64), 256, 0, stream>>>(hsb, wtb, bq, bk, bv, qb, kb, vt);
  attn<<<dim3(16, 128), 256, 0, stream>>>(qb, kb, vt, eb, mask, out);
}

// Round 4
// 458.681 us; speedup vs baseline: 1.0767x; 1.0767x over previous
//
#include <hip/hip_runtime.h>
#include <stdint.h>

typedef unsigned short u16;
typedef short bf16x8 __attribute__((ext_vector_type(8)));
typedef float f32x4 __attribute__((ext_vector_type(4)));
typedef u16 u16x8 __attribute__((ext_vector_type(8)));
typedef u16 u16x4 __attribute__((ext_vector_type(4)));

#define NB 8
#define NS 1024
#define NH 16
#define NDH 64
#define ND 1024

#define AS1 __attribute__((address_space(1)))
#define AS3 __attribute__((address_space(3)))

// swizzled byte offset for u2/w2: row stride 128B, XOR row&7 into byte bits 4..6
__device__ __forceinline__ int SWZ(int row, int colbyte){
  return (row << 7) + (colbyte ^ ((row & 7) << 4));
}

__device__ __forceinline__ u16 f2b(float x){
  unsigned u = __float_as_uint(x);
  u += 0x7FFFu + ((u >> 16) & 1u);          // RNE
  return (u16)(u >> 16);
}
__device__ __forceinline__ float b2f(u16 h){ return __uint_as_float(((unsigned)h) << 16); }

// ---------------- cast f32 -> bf16 (n multiple of 8) ----------------
__global__ void cast_f32_bf16(const float* __restrict__ in, u16* __restrict__ out, long n){
  long i = ((long)blockIdx.x * blockDim.x + threadIdx.x) * 8;
  if (i + 8 <= n){
    float4 a = *(const float4*)&in[i];
    float4 b = *(const float4*)&in[i + 4];
    u16x8 o;
    o[0]=f2b(a.x); o[1]=f2b(a.y); o[2]=f2b(a.z); o[3]=f2b(a.w);
    o[4]=f2b(b.x); o[5]=f2b(b.y); o[6]=f2b(b.z); o[7]=f2b(b.w);
    *(u16x8*)&out[i] = o;
  }
}

// ---------------- transpose W (fp32 [k][n]) -> wt bf16 [p*1024+n][k] ----------------
__global__ void transpose_w(const float* __restrict__ Wq, const float* __restrict__ Wk,
                            const float* __restrict__ Wv, u16* __restrict__ wt){
  __shared__ float tile[64][65];
  int p = blockIdx.z;
  const float* W = (p == 0) ? Wq : ((p == 1) ? Wk : Wv);
  int n0 = blockIdx.x * 64, k0 = blockIdx.y * 64;
  int t = threadIdx.x;
  int row = t >> 2, cb = (t & 3) * 16;
  #pragma unroll
  for (int cc = 0; cc < 4; ++cc){
    float4 v = *(const float4*)&W[(size_t)(k0 + row) * ND + n0 + cb + cc * 4];
    tile[row][cb + cc*4 + 0] = v.x; tile[row][cb + cc*4 + 1] = v.y;
    tile[row][cb + cc*4 + 2] = v.z; tile[row][cb + cc*4 + 3] = v.w;
  }
  __syncthreads();
  u16x8 o0, o1;
  #pragma unroll
  for (int kk = 0; kk < 8; ++kk) o0[kk] = f2b(tile[cb + kk][row]);
  #pragma unroll
  for (int kk = 0; kk < 8; ++kk) o1[kk] = f2b(tile[cb + 8 + kk][row]);
  size_t ob = ((size_t)(p * ND + n0 + row)) * ND + k0 + cb;
  *(u16x8*)&wt[ob]     = o0;
  *(u16x8*)&wt[ob + 8] = o1;
}

// ---------------- QKV GEMM (unchanged) ----------------
__global__ __launch_bounds__(256) void qkv_gemm(
    const u16* __restrict__ hsb, const u16* __restrict__ wtb,
    const float* __restrict__ bq, const float* __restrict__ bk, const float* __restrict__ bv,
    u16* __restrict__ qb, u16* __restrict__ kb, u16* __restrict__ vt){
  __shared__ __attribute__((aligned(16))) u16 Al[128 * 32];
  __shared__ __attribute__((aligned(16))) u16 Bl[128 * 32];
  int t = threadIdx.x;
  int lane = t & 63, w = t >> 6;
  int li = lane & 15, g = lane >> 4;
  int m0 = blockIdx.y * 128, n0 = blockIdx.x * 128;
  int wm = (w >> 1) * 64, wn = (w & 1) * 64;
  f32x4 acc[4][4];
  #pragma unroll
  for (int a = 0; a < 4; ++a)
    #pragma unroll
    for (int b = 0; b < 4; ++b){ f32x4 z = {0.f,0.f,0.f,0.f}; acc[a][b] = z; }

  for (int kt = 0; kt < 32; ++kt){
    __syncthreads();
    #pragma unroll
    for (int ph = 0; ph < 2; ++ph){
      int c = ph * 256 + t;            // chunk 0..511 (16B each)
      int row = c >> 2, ch = c & 3;
      const u16* ga = &hsb[(size_t)(m0 + row) * ND + kt * 32 + ch * 8];
      __builtin_amdgcn_global_load_lds((const AS1 void*)ga,
          (AS3 void*)&Al[(ph * 256 + w * 64) * 8], 16, 0, 0);
      const u16* gb = &wtb[(size_t)(n0 + row) * ND + kt * 32 + ch * 8];
      __builtin_amdgcn_global_load_lds((const AS1 void*)gb,
          (AS3 void*)&Bl[(ph * 256 + w * 64) * 8], 16, 0, 0);
    }
    asm volatile("s_waitcnt vmcnt(0)" ::: "memory");
    __syncthreads();
    bf16x8 af[4], bfr[4];
    #pragma unroll
    for (int mt = 0; mt < 4; ++mt)
      af[mt] = *(const bf16x8*)&Al[(wm + mt * 16 + li) * 32 + g * 8];
    #pragma unroll
    for (int nt = 0; nt < 4; ++nt)
      bfr[nt] = *(const bf16x8*)&Bl[(wn + nt * 16 + li) * 32 + g * 8];
    #pragma unroll
    for (int mt = 0; mt < 4; ++mt)
      #pragma unroll
      for (int nt = 0; nt < 4; ++nt)
        acc[mt][nt] = __builtin_amdgcn_mfma_f32_16x16x32_bf16(af[mt], bfr[nt], acc[mt][nt], 0, 0, 0);
  }

  int proj = n0 >> 10;
  const float* bias = (proj == 0) ? bq : ((proj == 1) ? bk : bv);
  #pragma unroll
  for (int nt = 0; nt < 4; ++nt){
    int n = n0 + wn + nt * 16 + li;
    int nc = n & 1023;
    float bv_ = bias[nc];
    #pragma unroll
    for (int mt = 0; mt < 4; ++mt){
      #pragma unroll
      for (int r = 0; r < 4; ++r){
        int m = m0 + wm + mt * 16 + g * 4 + r;
        u16 hv = f2b(acc[mt][nt][r] + bv_);
        if (proj == 0)      qb[(size_t)m * ND + nc] = hv;
        else if (proj == 1) kb[(size_t)m * ND + nc] = hv;
        else {
          int bb = m >> 10, s = m & 1023;
          int hh = nc >> 6, dh = nc & 63;
          vt[((size_t)(bb * NH + hh) * NDH + dh) * NS + s] = hv;
        }
      }
    }
  }
}

// ---------------- fused flash attention with relative_key_query bias ----------------
// R2 base + (1) E register ring: ehi[4][2] persists (upper window half = prev lower),
// only 4 new frag-pairs loaded per iter, consumed AFTER QK^T+upper-half MFMAs;
// (2) K/V T14 split: next tile's K/V prefetched to regs, b0->b1 is pure LDS writes.
__global__ __launch_bounds__(256, 3) void attn(
    const u16* __restrict__ qb, const u16* __restrict__ kb,
    const u16* __restrict__ vt, const u16* __restrict__ eb,
    const float* __restrict__ mask, float* __restrict__ out){
  __shared__ __attribute__((aligned(16))) u16 k_lds[64 * 72];
  __shared__ __attribute__((aligned(16))) u16 v_lds[64 * 72];
  __shared__ __attribute__((aligned(16))) u16 u2[128 * 64];   // U2[tt][i], swizzled; rows 0..63 reused as P
  __shared__ __attribute__((aligned(16))) u16 w2[128 * 64];   // W2[tt][j], swizzled

  int t = threadIdx.x, lane = t & 63, w = t >> 6;
  int li = lane & 15, g = lane >> 4;
  int lt = blockIdx.x, bh = blockIdx.y;
  int b = bh >> 4, h = bh & 15;
  int l0 = lt * 64;
  int iA  = w * 16 + g * 4;          // i base for this lane's score rows
  int iA2 = iA * 2;
  int li2 = li * 2;
  int ttc = iA + 63 - li;            // tt = ttc + r - 16*jt
  int colw = iA2;                    // u2/w2 write column byte base

  // Q A-frags (16 rows per wave), resident for all 16 K-tiles
  bf16x8 qf[2];
  {
    size_t qoff = ((size_t)(b * NS + l0 + w * 16 + li)) * ND + h * NDH;
    qf[0] = *(const bf16x8*)&qb[qoff + 0 + g * 8];
    qf[1] = *(const bf16x8*)&qb[qoff + 32 + g * 8];
  }

  // E ring init: upper half of the kt2=0 window (t_glob = l0+1024+trow', trow'=nt*16+li)
  bf16x8 ehi[4][2];
  #pragma unroll
  for (int nt = 0; nt < 4; ++nt){
    int er = l0 + 1024 + nt * 16 + li;
    if (er > 2046) er = 2046;        // row 127 of any window is never gathered
    #pragma unroll
    for (int k2 = 0; k2 < 2; ++k2)
      ehi[nt][k2] = *(const bf16x8*)&eb[(size_t)er * NDH + k2 * 32 + g * 8];
  }

  // K/V prefetch for tile 0
  u16x8 rk[2], rv[2];
  {
    #pragma unroll
    for (int ph = 0; ph < 2; ++ph){
      int c = ph * 256 + t, row = c >> 3, ch = c & 7;
      rk[ph] = *(const u16x8*)&kb[((size_t)(b * NS + row)) * ND + h * NDH + ch * 8];
      rv[ph] = *(const u16x8*)&vt[((size_t)(bh * NDH + row)) * NS + ch * 8];
    }
  }

  f32x4 oacc[4];
  #pragma unroll
  for (int i = 0; i < 4; ++i){ f32x4 z = {0.f,0.f,0.f,0.f}; oacc[i] = z; }
  float mold[4] = {-1e30f, -1e30f, -1e30f, -1e30f};
  float lsum[4] = {0.f, 0.f, 0.f, 0.f};

  for (int kt2 = 0; kt2 < 16; ++kt2){
    int r0 = kt2 * 64;
    int ebase = l0 - r0 + 960;       // window t_glob in [ebase, ebase+127]

    __syncthreads();                 // b0: prev iter LDS reads done before restage
    #pragma unroll
    for (int ph = 0; ph < 2; ++ph){
      int c = ph * 256 + t, row = c >> 3, ch = c & 7;
      *(u16x8*)&k_lds[row * 72 + ch * 8] = rk[ph];
      *(u16x8*)&v_lds[row * 72 + ch * 8] = rv[ph];
    }
    __syncthreads();                 // b1: k/v staged

    // ---- prefetch next tile's K/V into regs (lands during this iter's compute) ----
    {
      int rn = ((kt2 + 1) & 15) * 64;
      #pragma unroll
      for (int ph = 0; ph < 2; ++ph){
        int c = ph * 256 + t, row = c >> 3, ch = c & 7;
        rk[ph] = *(const u16x8*)&kb[((size_t)(b * NS + rn + row)) * ND + h * NDH + ch * 8];
        rv[ph] = *(const u16x8*)&vt[((size_t)(bh * NDH + row)) * NS + rn + ch * 8];
      }
    }

    // ---- issue new lower-half E frags (consumed after QK^T + upper-half MFMAs) ----
    bf16x8 elo[4][2];
    #pragma unroll
    for (int nt = 0; nt < 4; ++nt){
      int er = ebase + nt * 16 + li;                 // in [0, 1983] — no clamp needed
      #pragma unroll
      for (int k2 = 0; k2 < 2; ++k2)
        elo[nt][k2] = *(const bf16x8*)&eb[(size_t)er * NDH + k2 * 32 + g * 8];
    }

    // k A-frags (this wave's 16 j rows) for W2
    bf16x8 kf[2];
    kf[0] = *(const bf16x8*)&k_lds[(w * 16 + li) * 72 + 0 + g * 8];
    kf[1] = *(const bf16x8*)&k_lds[(w * 16 + li) * 72 + 32 + g * 8];

    // QK^T: this wave's 16 q-rows x 64 cols (independent of E loads)
    f32x4 sacc[4];
    #pragma unroll
    for (int jt = 0; jt < 4; ++jt){
      f32x4 z = {0.f,0.f,0.f,0.f}; sacc[jt] = z;
      #pragma unroll
      for (int k2 = 0; k2 < 2; ++k2){
        bf16x8 kbf = *(const bf16x8*)&k_lds[(jt * 16 + li) * 72 + k2 * 32 + g * 8];
        sacc[jt] = __builtin_amdgcn_mfma_f32_16x16x32_bf16(qf[k2], kbf, sacc[jt], 0, 0, 0);
      }
    }

    // U2/W2 upper half (trow 64..127) from resident ring regs
    #pragma unroll
    for (int nt = 4; nt < 8; ++nt){
      int trow = nt * 16 + li;
      f32x4 ua = {0.f,0.f,0.f,0.f}, wa = {0.f,0.f,0.f,0.f};
      #pragma unroll
      for (int k2 = 0; k2 < 2; ++k2){
        ua = __builtin_amdgcn_mfma_f32_16x16x32_bf16(qf[k2], ehi[nt - 4][k2], ua, 0, 0, 0);
        wa = __builtin_amdgcn_mfma_f32_16x16x32_bf16(kf[k2], ehi[nt - 4][k2], wa, 0, 0, 0);
      }
      u16x4 up, wp;
      #pragma unroll
      for (int r = 0; r < 4; ++r){ up[r] = f2b(ua[r]); wp[r] = f2b(wa[r]); }
      *(u16x4*)((char*)u2 + SWZ(trow, colw)) = up;
      *(u16x4*)((char*)w2 + SWZ(trow, colw)) = wp;
    }
    // U2/W2 lower half (trow 0..63) from freshly loaded frags
    #pragma unroll
    for (int nt = 0; nt < 4; ++nt){
      int trow = nt * 16 + li;
      f32x4 ua = {0.f,0.f,0.f,0.f}, wa = {0.f,0.f,0.f,0.f};
      #pragma unroll
      for (int k2 = 0; k2 < 2; ++k2){
        ua = __builtin_amdgcn_mfma_f32_16x16x32_bf16(qf[k2], elo[nt][k2], ua, 0, 0, 0);
        wa = __builtin_amdgcn_mfma_f32_16x16x32_bf16(kf[k2], elo[nt][k2], wa, 0, 0, 0);
      }
      u16x4 up, wp;
      #pragma unroll
      for (int r = 0; r < 4; ++r){ up[r] = f2b(ua[r]); wp[r] = f2b(wa[r]); }
      *(u16x4*)((char*)u2 + SWZ(trow, colw)) = up;
      *(u16x4*)((char*)w2 + SWZ(trow, colw)) = wp;
    }
    // rotate ring: next window's upper half = this window's lower half
    #pragma unroll
    for (int nt = 0; nt < 4; ++nt){
      ehi[nt][0] = elo[nt][0];
      ehi[nt][1] = elo[nt][1];
    }
    __syncthreads();                 // b2: U2/W2 visible

    // gather diagonal bias + assemble scores
    float sv[4][4];
    #pragma unroll
    for (int jt = 0; jt < 4; ++jt){
      float mk = mask[b * NS + r0 + jt * 16 + li];
      int j2 = jt * 32 + li2;
      #pragma unroll
      for (int r = 0; r < 4; ++r){
        int tt = ttc + r - jt * 16;
        int byU = (tt << 7) + ((iA2 + 2 * r) ^ ((tt & 7) << 4));
        int byW = (tt << 7) + (j2 ^ ((tt & 7) << 4));
        float u  = b2f(*(const u16*)((const char*)u2 + byU));
        float ww = b2f(*(const u16*)((const char*)w2 + byW));
        sv[jt][r] = sacc[jt][r] * 0.125f + u + ww + mk;
      }
    }

    // online softmax (rows live in 16-lane groups)
    float rmax[4], rsum[4];
    #pragma unroll
    for (int r = 0; r < 4; ++r)
      rmax[r] = fmaxf(fmaxf(sv[0][r], sv[1][r]), fmaxf(sv[2][r], sv[3][r]));
    #pragma unroll
    for (int xm = 1; xm <= 8; xm <<= 1)
      #pragma unroll
      for (int r = 0; r < 4; ++r)
        rmax[r] = fmaxf(rmax[r], __shfl_xor(rmax[r], xm));
    float mnew[4], fac[4];
    #pragma unroll
    for (int r = 0; r < 4; ++r){
      mnew[r] = fmaxf(mold[r], rmax[r]);
      fac[r]  = __expf(mold[r] - mnew[r]);
    }
    float pr[4][4];
    #pragma unroll
    for (int r = 0; r < 4; ++r) rsum[r] = 0.f;
    #pragma unroll
    for (int jt = 0; jt < 4; ++jt)
      #pragma unroll
      for (int r = 0; r < 4; ++r){
        pr[jt][r] = __expf(sv[jt][r] - mnew[r]);
        rsum[r] += pr[jt][r];
      }
    #pragma unroll
    for (int xm = 1; xm <= 8; xm <<= 1)
      #pragma unroll
      for (int r = 0; r < 4; ++r)
        rsum[r] += __shfl_xor(rsum[r], xm);
    #pragma unroll
    for (int r = 0; r < 4; ++r){
      lsum[r] = lsum[r] * fac[r] + rsum[r];
      mold[r] = mnew[r];
    }
    #pragma unroll
    for (int nt2 = 0; nt2 < 4; ++nt2)
      #pragma unroll
      for (int r = 0; r < 4; ++r)
        oacc[nt2][r] *= fac[r];

    __syncthreads();                 // b3: gathers done; u2 rows 0..63 reusable as P
    #pragma unroll
    for (int jt = 0; jt < 4; ++jt)
      #pragma unroll
      for (int r = 0; r < 4; ++r){
        int prow = w * 16 + g * 4 + r;
        *(u16*)((char*)u2 + SWZ(prow, jt * 32 + li2)) = f2b(pr[jt][r]);
      }

    // PV: O += P @ V   (A=P rows i from u2 strip, B=V^T rows dh from v_lds)
    #pragma unroll
    for (int k2 = 0; k2 < 2; ++k2){
      bf16x8 pf = *(const bf16x8*)((const char*)u2 + SWZ(w * 16 + li, k2 * 64 + g * 16));
      #pragma unroll
      for (int nt2 = 0; nt2 < 4; ++nt2){
        bf16x8 vf = *(const bf16x8*)&v_lds[(nt2 * 16 + li) * 72 + k2 * 32 + g * 8];
        oacc[nt2] = __builtin_amdgcn_mfma_f32_16x16x32_bf16(pf, vf, oacc[nt2], 0, 0, 0);
      }
    }
  }

  // epilogue: O / lsum -> out fp32 [B,S,D]
  #pragma unroll
  for (int nt2 = 0; nt2 < 4; ++nt2)
    #pragma unroll
    for (int r = 0; r < 4; ++r){
      int row = l0 + w * 16 + g * 4 + r;
      out[((size_t)(b * NS + row)) * ND + h * NDH + nt2 * 16 + li] = oacc[nt2][r] / lsum[r];
    }
}

extern "C" void kernel_launch(void* const* d_in, const int* in_sizes, int n_in,
                              void* d_out, int out_size, void* d_ws, size_t ws_size,
                              hipStream_t stream){
  (void)in_sizes; (void)n_in; (void)out_size; (void)ws_size;
  const float* hs   = (const float*)d_in[0];
  const float* mask = (const float*)d_in[1];
  const float* Wq   = (const float*)d_in[2];
  const float* bq   = (const float*)d_in[3];
  const float* Wk   = (const float*)d_in[4];
  const float* bk   = (const float*)d_in[5];
  const float* Wv   = (const float*)d_in[6];
  const float* bv   = (const float*)d_in[7];
  const float* de   = (const float*)d_in[8];
  float* out = (float*)d_out;
  char* ws = (char*)d_ws;

  u16* hsb = (u16*)(ws);                    // 16,777,216 B
  u16* wtb = (u16*)(ws + 16777216);         //  6,291,456 B
  u16* eb  = (u16*)(ws + 23068672);         //    262,016 B (+pad)
  u16* qb  = (u16*)(ws + 23330816);         // 16,777,216 B
  u16* kb  = (u16*)(ws + 40108032);         // 16,777,216 B
  u16* vt  = (u16*)(ws + 56885248);         // 16,777,216 B  -> total ~70.2 MB

  cast_f32_bf16<<<4096, 256, 0, stream>>>(hs, hsb, 8388608L);
  cast_f32_bf16<<<64, 256, 0, stream>>>(de, eb, 131008L);
  transpose_w<<<dim3(16, 16, 3), 256, 0, stream>>>(Wq, Wk, Wv, wtb);
  qkv_gemm<<<dim3(24, 64), 256, 0, stream>>>(hsb, wtb, bq, bk, bv, qb, kb, vt);
  attn<<<dim3(16, 128), 256, 0, stream>>>(qb, kb, vt, eb, mask, out);
}